// Round 9
// baseline (388.526 us; speedup 1.0000x reference)
//
#include <hip/hip_runtime.h>
#include <hip/hip_fp16.h>

// Problem constants (fixed by the reference setup)
#define N_NODES 50000
#define IN_DIM 256
#define OUT_DIM 128
#define NNZ 800000          // nnz for feat, adj1, adj2 each
#define SCAN_N (3 * N_NODES)        // 150000 row counters (feat | adj1 | adj2)
#define TOTAL_NNZ (3 * NNZ)         // 2.4M sorted entries
#define SCAN_BLOCKS ((SCAN_N + 255) / 256)   // 586
#define NPART 8                      // one row-partition per XCD
#define PART_W (N_NODES / NPART)     // 6250 rows per partition
#define W_ELEMS (IN_DIM * OUT_DIM)   // 32768 per matrix

// Native clang vector types — __builtin_nontemporal_* requires these.
typedef float vf4 __attribute__((ext_vector_type(4)));

// Packed entry: [col:16 | fp16(val):16].  adj cols < 50000 < 65536, feat cols < 256.
static __device__ __forceinline__ unsigned pack_cv(int c, float v) {
    return ((unsigned)c << 16) | (unsigned)__half_as_ushort(__float2half(v));
}
static __device__ __forceinline__ int   upk_c(unsigned pk) { return (int)(pk >> 16); }
static __device__ __forceinline__ float upk_v(unsigned pk) {
    return __half2float(__ushort_as_half((unsigned short)(pk & 0xffffu)));
}
static __device__ __forceinline__ float h2f(unsigned short h) {
    return __half2float(__ushort_as_half(h));
}

// -----------------------------------------------------------------------------
// W fp32 -> fp16 conversion (once per launch; 64K elements total).
// -----------------------------------------------------------------------------
__global__ void wconv_kernel(const float* __restrict__ W1,
                             const float* __restrict__ W2,
                             ushort* __restrict__ w1h,
                             ushort* __restrict__ w2h) {
    int i = blockIdx.x * blockDim.x + threadIdx.x;
    if (i < W_ELEMS) {
        w1h[i] = __half_as_ushort(__float2half(W1[i]));
        w2h[i] = __half_as_ushort(__float2half(W2[i]));
    }
}

// -----------------------------------------------------------------------------
// CSR build: histogram -> exclusive scan -> scatter (counting sort by row).
// Unified segments: feat rows [0,50K), adj1 [50K,100K), adj2 [100K,150K).
//
// XCD partitioning: rows are split into 8 contiguous ranges (part = r/6250).
// blockIdx&7 round-robins across XCDs, so all atomics/stores for a given row
// come from ONE XCD -> its L2 merges same-line stores instead of bouncing.
// Input loads are CACHED (not nt!): 8 partitions re-read the same lines, and
// L2/L3 must serve re-reads (nt here cost 112 MB of HBM FETCH in R8).
// -----------------------------------------------------------------------------
__global__ void hist_kernel(const int* __restrict__ fr,
                            const int* __restrict__ a1r,
                            const int* __restrict__ a2r,
                            int* __restrict__ cnt) {
    int part = blockIdx.x & (NPART - 1);
    int e = (blockIdx.x >> 3) * blockDim.x + threadIdx.x;
    if (e >= NNZ) return;
    int a = fr[e];
    if (a / PART_W == part) atomicAdd(&cnt[a], 1);
    int b = a1r[e];
    if (b / PART_W == part) atomicAdd(&cnt[N_NODES + b], 1);
    int c = a2r[e];
    if (c / PART_W == part) atomicAdd(&cnt[2 * N_NODES + c], 1);
}

__global__ void scan_block_kernel(const int* __restrict__ cnt,
                                  int* __restrict__ starts,
                                  int* __restrict__ bsum) {
    __shared__ int tmp[256];
    int g = blockIdx.x * 256 + threadIdx.x;
    int v = (g < SCAN_N) ? cnt[g] : 0;
    tmp[threadIdx.x] = v;
    __syncthreads();
    for (int off = 1; off < 256; off <<= 1) {
        int t = (threadIdx.x >= off) ? tmp[threadIdx.x - off] : 0;
        __syncthreads();
        tmp[threadIdx.x] += t;
        __syncthreads();
    }
    int incl = tmp[threadIdx.x];
    if (g < SCAN_N) starts[g] = incl - v;          // exclusive
    if (threadIdx.x == 255) bsum[blockIdx.x] = incl;
}

__global__ void scan_bsum_kernel(int* __restrict__ bsum, int nb) {
    __shared__ int tmp[1024];
    int t = threadIdx.x;
    int v = (t < nb) ? bsum[t] : 0;
    tmp[t] = v;
    __syncthreads();
    for (int off = 1; off < 1024; off <<= 1) {
        int x = (t >= off) ? tmp[t - off] : 0;
        __syncthreads();
        tmp[t] += x;
        __syncthreads();
    }
    if (t < nb) bsum[t] = tmp[t] - v;              // exclusive block offsets
}

__global__ void scan_add_kernel(int* __restrict__ starts,
                                const int* __restrict__ bsum,
                                int* __restrict__ cursor) {
    int g = blockIdx.x * 256 + threadIdx.x;
    if (g < SCAN_N) {
        int s = starts[g] + bsum[blockIdx.x];
        starts[g] = s;
        cursor[g] = s;
    }
}

// XCD-partitioned scatter with cached input loads.
__global__ void scatter_kernel(const int* __restrict__ fr, const int* __restrict__ fc,
                               const float* __restrict__ fv,
                               const int* __restrict__ a1r, const int* __restrict__ a1c,
                               const float* __restrict__ a1v,
                               const int* __restrict__ a2r, const int* __restrict__ a2c,
                               const float* __restrict__ a2v,
                               int* __restrict__ cursor,
                               unsigned* __restrict__ spack) {
    int part = blockIdx.x & (NPART - 1);
    int e = (blockIdx.x >> 3) * blockDim.x + threadIdx.x;
    if (e >= NNZ) return;
    int r = fr[e];
    if (r / PART_W == part) {
        int p = atomicAdd(&cursor[r], 1);
        spack[p] = pack_cv(fc[e], fv[e]);
    }
    int r1 = a1r[e];
    if (r1 / PART_W == part) {
        int p = atomicAdd(&cursor[N_NODES + r1], 1);
        spack[p] = pack_cv(a1c[e], a1v[e]);
    }
    int r2 = a2r[e];
    if (r2 / PART_W == part) {
        int p = atomicAdd(&cursor[2 * N_NODES + r2], 1);
        spack[p] = pack_cv(a2c[e], a2v[e]);
    }
}

// -----------------------------------------------------------------------------
// Phase 1: per-row gather  xw{1,2}[r,:] = sum_e v_e * W{1,2}[c_e,:]
// 32-lane row group; shfl-broadcast of packed records; x4 unroll = 8
// independent fp16 W loads (8B/lane) in flight. xw output fp16.
// -----------------------------------------------------------------------------
__global__ void feat_gather_kernel(const int* __restrict__ starts,
                                   const unsigned* __restrict__ spack,
                                   const ushort4* __restrict__ w1h,
                                   const ushort4* __restrict__ w2h,
                                   ushort4* __restrict__ xw1h,
                                   ushort4* __restrict__ xw2h) {
    int lane = threadIdx.x & 31;
    int sub  = threadIdx.x >> 5;
    int r = blockIdx.x * 8 + sub;
    if (r >= N_NODES) return;
    int s = starts[r];
    int e = starts[r + 1];            // starts[50000] == 800000 (adj1 base)
    float4 a1 = make_float4(0.f, 0.f, 0.f, 0.f);
    float4 a2 = make_float4(0.f, 0.f, 0.f, 0.f);
    for (int base = s; base < e; base += 32) {
        int n = e - base;
        int m = (n < 32) ? n : 32;
        unsigned pk = (lane < m) ? spack[base + lane] : 0u;
        int j = 0;
        for (; j + 3 < m; j += 4) {
            unsigned p0 = __shfl(pk, j,     32);
            unsigned p1 = __shfl(pk, j + 1, 32);
            unsigned p2 = __shfl(pk, j + 2, 32);
            unsigned p3 = __shfl(pk, j + 3, 32);
            int c0 = upk_c(p0), c1 = upk_c(p1), c2 = upk_c(p2), c3 = upk_c(p3);
            float v0 = upk_v(p0), v1 = upk_v(p1), v2 = upk_v(p2), v3 = upk_v(p3);
            ushort4 u10 = w1h[c0 * 32 + lane], u20 = w2h[c0 * 32 + lane];
            ushort4 u11 = w1h[c1 * 32 + lane], u21 = w2h[c1 * 32 + lane];
            ushort4 u12 = w1h[c2 * 32 + lane], u22 = w2h[c2 * 32 + lane];
            ushort4 u13 = w1h[c3 * 32 + lane], u23 = w2h[c3 * 32 + lane];
            a1.x += v0 * h2f(u10.x); a1.y += v0 * h2f(u10.y);
            a1.z += v0 * h2f(u10.z); a1.w += v0 * h2f(u10.w);
            a2.x += v0 * h2f(u20.x); a2.y += v0 * h2f(u20.y);
            a2.z += v0 * h2f(u20.z); a2.w += v0 * h2f(u20.w);
            a1.x += v1 * h2f(u11.x); a1.y += v1 * h2f(u11.y);
            a1.z += v1 * h2f(u11.z); a1.w += v1 * h2f(u11.w);
            a2.x += v1 * h2f(u21.x); a2.y += v1 * h2f(u21.y);
            a2.z += v1 * h2f(u21.z); a2.w += v1 * h2f(u21.w);
            a1.x += v2 * h2f(u12.x); a1.y += v2 * h2f(u12.y);
            a1.z += v2 * h2f(u12.z); a1.w += v2 * h2f(u12.w);
            a2.x += v2 * h2f(u22.x); a2.y += v2 * h2f(u22.y);
            a2.z += v2 * h2f(u22.z); a2.w += v2 * h2f(u22.w);
            a1.x += v3 * h2f(u13.x); a1.y += v3 * h2f(u13.y);
            a1.z += v3 * h2f(u13.z); a1.w += v3 * h2f(u13.w);
            a2.x += v3 * h2f(u23.x); a2.y += v3 * h2f(u23.y);
            a2.z += v3 * h2f(u23.z); a2.w += v3 * h2f(u23.w);
        }
        for (; j < m; ++j) {
            unsigned pj = __shfl(pk, j, 32);
            int c = upk_c(pj);
            float v = upk_v(pj);
            ushort4 u1 = w1h[c * 32 + lane];
            ushort4 u2 = w2h[c * 32 + lane];
            a1.x += v * h2f(u1.x); a1.y += v * h2f(u1.y);
            a1.z += v * h2f(u1.z); a1.w += v * h2f(u1.w);
            a2.x += v * h2f(u2.x); a2.y += v * h2f(u2.y);
            a2.z += v * h2f(u2.z); a2.w += v * h2f(u2.w);
        }
    }
    ushort4 q1, q2;
    q1.x = __half_as_ushort(__float2half(a1.x)); q1.y = __half_as_ushort(__float2half(a1.y));
    q1.z = __half_as_ushort(__float2half(a1.z)); q1.w = __half_as_ushort(__float2half(a1.w));
    q2.x = __half_as_ushort(__float2half(a2.x)); q2.y = __half_as_ushort(__float2half(a2.y));
    q2.z = __half_as_ushort(__float2half(a2.z)); q2.w = __half_as_ushort(__float2half(a2.w));
    xw1h[r * 32 + lane] = q1;
    xw2h[r * 32 + lane] = q2;
}

// -----------------------------------------------------------------------------
// Phase 2: out[r,:] = relu( sum_adj1 v*xw1[c,:] + sum_adj2 v*xw2[c,:] )
// adj1+adj2 edge ranges CONCATENATED into one stream and unrolled x8 so 8
// independent xw gathers are in flight (was 4) — kernel is latency-bound.
// -----------------------------------------------------------------------------
__global__ void adj_gather_kernel(const int* __restrict__ starts,
                                  const unsigned* __restrict__ spack,
                                  const ushort4* __restrict__ xw1h,
                                  const ushort4* __restrict__ xw2h,
                                  vf4* __restrict__ out) {
    int lane = threadIdx.x & 31;
    int sub  = threadIdx.x >> 5;
    int r = blockIdx.x * 8 + sub;
    if (r >= N_NODES) return;

    int s1 = starts[N_NODES + r];
    int e1 = starts[N_NODES + r + 1];        // starts[100000] == adj2 base
    int s2 = starts[2 * N_NODES + r];
    int e2 = (r == N_NODES - 1) ? TOTAL_NNZ : starts[2 * N_NODES + r + 1];
    int len1 = e1 - s1;
    int mtot = len1 + (e2 - s2);

    float4 acc = make_float4(0.f, 0.f, 0.f, 0.f);

    for (int base = 0; base < mtot; base += 32) {
        int n = mtot - base;
        int m = (n < 32) ? n : 32;
        int gi = base + lane;
        int pos = (gi < len1) ? (s1 + gi) : (s2 + gi - len1);
        unsigned pk = (lane < m) ? spack[pos] : 0u;

        int j = 0;
        for (; j + 7 < m; j += 8) {
            unsigned pv[8];
            #pragma unroll
            for (int k = 0; k < 8; ++k) pv[k] = __shfl(pk, j + k, 32);
            ushort4 xv[8];
            #pragma unroll
            for (int k = 0; k < 8; ++k) {
                int gj = base + j + k;
                const ushort4* __restrict__ xw = (gj < len1) ? xw1h : xw2h;
                xv[k] = xw[upk_c(pv[k]) * 32 + lane];
            }
            #pragma unroll
            for (int k = 0; k < 8; ++k) {
                float v = upk_v(pv[k]);
                acc.x += v * h2f(xv[k].x); acc.y += v * h2f(xv[k].y);
                acc.z += v * h2f(xv[k].z); acc.w += v * h2f(xv[k].w);
            }
        }
        for (; j < m; ++j) {
            unsigned pj = __shfl(pk, j, 32);
            int gj = base + j;
            const ushort4* __restrict__ xw = (gj < len1) ? xw1h : xw2h;
            ushort4 x = xw[upk_c(pj) * 32 + lane];
            float v = upk_v(pj);
            acc.x += v * h2f(x.x); acc.y += v * h2f(x.y);
            acc.z += v * h2f(x.z); acc.w += v * h2f(x.w);
        }
    }
    vf4 res;
    res.x = fmaxf(acc.x, 0.f); res.y = fmaxf(acc.y, 0.f);
    res.z = fmaxf(acc.z, 0.f); res.w = fmaxf(acc.w, 0.f);
    __builtin_nontemporal_store(res, &out[r * 32 + lane]);
}

extern "C" void kernel_launch(void* const* d_in, const int* in_sizes, int n_in,
                              void* d_out, int out_size, void* d_ws, size_t ws_size,
                              hipStream_t stream) {
    const int*   feat_row  = (const int*)  d_in[0];
    const int*   feat_col  = (const int*)  d_in[1];
    const float* feat_vals = (const float*)d_in[2];
    const int*   adj1_row  = (const int*)  d_in[3];
    const int*   adj1_col  = (const int*)  d_in[4];
    const float* adj1_vals = (const float*)d_in[5];
    const int*   adj2_row  = (const int*)  d_in[6];
    const int*   adj2_col  = (const int*)  d_in[7];
    const float* adj2_vals = (const float*)d_in[8];
    const float* W1        = (const float*)d_in[9];
    const float* W2        = (const float*)d_in[10];

    // Workspace layout (all 16B-aligned offsets)
    char* ws = (char*)d_ws;
    ushort4*  xw1h  = (ushort4*)ws;             ws += (size_t)N_NODES * OUT_DIM * 2;  // 12.8 MB
    ushort4*  xw2h  = (ushort4*)ws;             ws += (size_t)N_NODES * OUT_DIM * 2;  // 12.8 MB
    unsigned* spack = (unsigned*)ws;            ws += (size_t)TOTAL_NNZ * 4;          // 9.6 MB
    ushort*   w1h   = (ushort*)ws;              ws += (size_t)W_ELEMS * 2;            // 64 KB
    ushort*   w2h   = (ushort*)ws;              ws += (size_t)W_ELEMS * 2;            // 64 KB
    int*      cnt   = (int*)ws;                 ws += (size_t)SCAN_N * 4;             // 600 KB
    int*      starts= (int*)ws;                 ws += (size_t)SCAN_N * 4;             // 600 KB
    int*      cursor= (int*)ws;                 ws += (size_t)SCAN_N * 4;             // 600 KB
    int*      bsum  = (int*)ws;                 ws += 1024 * 4;

    // Zero only the histogram counters (everything else is fully overwritten).
    (void)hipMemsetAsync(cnt, 0, SCAN_N * sizeof(int), stream);

    const int block = 256;

    wconv_kernel<<<(W_ELEMS + block - 1) / block, block, 0, stream>>>(
        W1, W2, w1h, w2h);

    // 8 partitions x 3125 chunks; blockIdx&7 = partition = XCD (round-robin).
    const int grid_part = NPART * ((NNZ + block - 1) / block);   // 25000
    hist_kernel<<<grid_part, block, 0, stream>>>(
        feat_row, adj1_row, adj2_row, cnt);

    scan_block_kernel<<<SCAN_BLOCKS, 256, 0, stream>>>(cnt, starts, bsum);
    scan_bsum_kernel<<<1, 1024, 0, stream>>>(bsum, SCAN_BLOCKS);
    scan_add_kernel<<<SCAN_BLOCKS, 256, 0, stream>>>(starts, bsum, cursor);

    scatter_kernel<<<grid_part, block, 0, stream>>>(
        feat_row, feat_col, feat_vals,
        adj1_row, adj1_col, adj1_vals,
        adj2_row, adj2_col, adj2_vals,
        cursor, spack);

    const int grid_rows = N_NODES / 8;                           // 6250 blocks, 8 rows each
    feat_gather_kernel<<<grid_rows, 256, 0, stream>>>(
        starts, spack, (const ushort4*)w1h, (const ushort4*)w2h, xw1h, xw2h);
    adj_gather_kernel<<<grid_rows, 256, 0, stream>>>(
        starts, spack, xw1h, xw2h, (vf4*)d_out);
}